// Round 2
// baseline (578.188 us; speedup 1.0000x reference)
//
#include <hip/hip_runtime.h>

// DepthProb: out[b,k,h,w] = softmax_k( -(feat[b,0,h,w] - depint[k])^2 )
// feat (4,1,512,1024) fp32, depint (64,) fp32, out (4,64,512,1024) fp32 = 537 MB.
//
// Round-1 post-mortem: single-kernel version wrote 64 x 1KiB chunks at 2MB
// stride per wave -> ~10^6 interleaved DRAM streams -> 2.8 TB/s (45% of what
// the harness's own fill achieves on this allocation at 10% occupancy).
// Fix: split into
//   1) dp_prep: per-pixel M = mn - ln(sum)  (8 MB to d_ws)   [compute-bound, ~20us]
//   2) dp_write: out = exp(M - (f-d_k)^2), each block sweeps 4 k-slabs with
//      long LINEAR store streams (fill-shaped writes)        [write-BW-bound, ~90us]
// Division is folded into M; dominant-bin cancellation is exact (recomputed
// (f-d)^2 bit-matches mn), so accuracy is unchanged.

#define KBINS 64
#define HW_SHIFT 19
#define HW (1 << HW_SHIFT)      // 512*1024 pixels per batch
#define NPIX (4 * HW)

// ---------------- kernel 1: per-pixel softmax stats -> M = mn - ln(sum) ----
__global__ __launch_bounds__(256) void dp_prep(
    const float* __restrict__ feat,
    const float* __restrict__ depint,
    float* __restrict__ Mout)
{
    __shared__ float sd[KBINS];
    if (threadIdx.x < KBINS) sd[threadIdx.x] = depint[threadIdx.x];
    __syncthreads();

    const int t  = blockIdx.x * 256 + threadIdx.x;
    const int p0 = t * 4;

    const float4 f4 = *reinterpret_cast<const float4*>(feat + p0);
    float f[4] = {f4.x, f4.y, f4.z, f4.w};

    float mn[4] = {1e30f, 1e30f, 1e30f, 1e30f};
    #pragma unroll
    for (int k = 0; k < KBINS; ++k) {
        const float d = sd[k];
        #pragma unroll
        for (int j = 0; j < 4; ++j) {
            const float df = f[j] - d;
            mn[j] = fminf(mn[j], df * df);
        }
    }

    float sum[4] = {0.f, 0.f, 0.f, 0.f};
    #pragma unroll
    for (int k = 0; k < KBINS; ++k) {
        const float d = sd[k];
        #pragma unroll
        for (int j = 0; j < 4; ++j) {
            const float df = f[j] - d;
            sum[j] += __expf(mn[j] - df * df);
        }
    }

    float4 m4;
    m4.x = mn[0] - __logf(sum[0]);
    m4.y = mn[1] - __logf(sum[1]);
    m4.z = mn[2] - __logf(sum[2]);
    m4.w = mn[3] - __logf(sum[3]);
    *reinterpret_cast<float4*>(Mout + p0) = m4;
}

// ---------------- kernel 2: linear-stream writer --------------------------
// grid = 2048 blocks x 256 threads. bid bits: [4:0]=chunk(32) [8:5]=kq(16) [10:9]=b(4).
// Block handles pixels [chunk*16384, chunk*16384+16384) of batch b for the
// 4 consecutive bins k = 4*kq .. 4*kq+3. Per iteration the block writes
// 4 KB contiguous per stream; 16 iterations sweep 64 KB linear per stream.
__global__ __launch_bounds__(256) void dp_write(
    const float* __restrict__ feat,
    const float* __restrict__ depint,
    const float* __restrict__ M,
    float* __restrict__ out)
{
    const int bid   = blockIdx.x;
    const int chunk = bid & 31;
    const int kq    = (bid >> 5) & 15;
    const int b     = bid >> 9;
    const int k0    = kq * 4;

    const float d0 = depint[k0 + 0];
    const float d1 = depint[k0 + 1];
    const float d2 = depint[k0 + 2];
    const float d3 = depint[k0 + 3];

    const float* fp = feat + ((size_t)b << HW_SHIFT);
    const float* mp = M    + ((size_t)b << HW_SHIFT);
    float* o0 = out + ((size_t)((b << 6) | k0) << HW_SHIFT);

    int q = (chunk << 14) + (threadIdx.x << 2);

    #pragma unroll
    for (int i = 0; i < 16; ++i) {
        const float4 f4 = *reinterpret_cast<const float4*>(fp + q);
        const float4 m4 = *reinterpret_cast<const float4*>(mp + q);
        const float f[4] = {f4.x, f4.y, f4.z, f4.w};
        const float m[4] = {m4.x, m4.y, m4.z, m4.w};

        float4 o;
        {   // k0
            float a0=f[0]-d0, a1=f[1]-d0, a2=f[2]-d0, a3=f[3]-d0;
            o.x=__expf(m[0]-a0*a0); o.y=__expf(m[1]-a1*a1);
            o.z=__expf(m[2]-a2*a2); o.w=__expf(m[3]-a3*a3);
            *reinterpret_cast<float4*>(o0 + q) = o;
        }
        {   // k0+1
            float a0=f[0]-d1, a1=f[1]-d1, a2=f[2]-d1, a3=f[3]-d1;
            o.x=__expf(m[0]-a0*a0); o.y=__expf(m[1]-a1*a1);
            o.z=__expf(m[2]-a2*a2); o.w=__expf(m[3]-a3*a3);
            *reinterpret_cast<float4*>(o0 + HW + q) = o;
        }
        {   // k0+2
            float a0=f[0]-d2, a1=f[1]-d2, a2=f[2]-d2, a3=f[3]-d2;
            o.x=__expf(m[0]-a0*a0); o.y=__expf(m[1]-a1*a1);
            o.z=__expf(m[2]-a2*a2); o.w=__expf(m[3]-a3*a3);
            *reinterpret_cast<float4*>(o0 + 2 * HW + q) = o;
        }
        {   // k0+3
            float a0=f[0]-d3, a1=f[1]-d3, a2=f[2]-d3, a3=f[3]-d3;
            o.x=__expf(m[0]-a0*a0); o.y=__expf(m[1]-a1*a1);
            o.z=__expf(m[2]-a2*a2); o.w=__expf(m[3]-a3*a3);
            *reinterpret_cast<float4*>(o0 + 3 * HW + q) = o;
        }
        q += 1024;
    }
}

// ---------------- fallback (round-1 single kernel, known-good) ------------
__global__ __launch_bounds__(256) void dp_fused(
    const float* __restrict__ feat,
    const float* __restrict__ depint,
    float* __restrict__ out)
{
    __shared__ float sd[KBINS];
    if (threadIdx.x < KBINS) sd[threadIdx.x] = depint[threadIdx.x];
    __syncthreads();

    const int t  = blockIdx.x * 256 + threadIdx.x;
    const int p0 = t * 4;

    const float4 f4 = *reinterpret_cast<const float4*>(feat + p0);
    float f[4] = {f4.x, f4.y, f4.z, f4.w};

    float mn[4] = {1e30f, 1e30f, 1e30f, 1e30f};
    #pragma unroll
    for (int k = 0; k < KBINS; ++k) {
        const float d = sd[k];
        #pragma unroll
        for (int j = 0; j < 4; ++j) { const float df = f[j] - d; mn[j] = fminf(mn[j], df * df); }
    }
    float sum[4] = {0.f, 0.f, 0.f, 0.f};
    #pragma unroll
    for (int k = 0; k < KBINS; ++k) {
        const float d = sd[k];
        #pragma unroll
        for (int j = 0; j < 4; ++j) { const float df = f[j] - d; sum[j] += __expf(mn[j] - df * df); }
    }
    float rs[4];
    #pragma unroll
    for (int j = 0; j < 4; ++j) rs[j] = 1.0f / sum[j];

    const int b = p0 >> HW_SHIFT;
    const int q = p0 & (HW - 1);
    float* op = out + ((size_t)b << (HW_SHIFT + 6)) + q;
    #pragma unroll
    for (int k = 0; k < KBINS; ++k) {
        const float d = sd[k];
        float4 o;
        const float a0 = f[0]-d, a1 = f[1]-d, a2 = f[2]-d, a3 = f[3]-d;
        o.x = __expf(mn[0]-a0*a0)*rs[0]; o.y = __expf(mn[1]-a1*a1)*rs[1];
        o.z = __expf(mn[2]-a2*a2)*rs[2]; o.w = __expf(mn[3]-a3*a3)*rs[3];
        *reinterpret_cast<float4*>(op) = o;
        op += HW;
    }
}

extern "C" void kernel_launch(void* const* d_in, const int* in_sizes, int n_in,
                              void* d_out, int out_size, void* d_ws, size_t ws_size,
                              hipStream_t stream) {
    const float* feat   = (const float*)d_in[0];
    const float* depint = (const float*)d_in[1];
    float* out = (float*)d_out;

    if (ws_size >= (size_t)NPIX * sizeof(float)) {
        float* Mws = (float*)d_ws;
        dp_prep <<<NPIX / 4 / 256, 256, 0, stream>>>(feat, depint, Mws);
        dp_write<<<2048,           256, 0, stream>>>(feat, depint, Mws, out);
    } else {
        dp_fused<<<NPIX / 4 / 256, 256, 0, stream>>>(feat, depint, out);
    }
}